// Round 13
// baseline (80.459 us; speedup 1.0000x reference)
//
#include <hip/hip_runtime.h>

typedef _Float16 half8 __attribute__((ext_vector_type(8)));
typedef float f32x4 __attribute__((ext_vector_type(4)));
typedef unsigned int u32x4 __attribute__((ext_vector_type(4)));

#define DD 128

// Workspace layout:
//   FRAG (R2-verified): nch records of 8192 B. Record c, octet idx=(s*2+hl)
//         at idx*1024 + lane*16: 8 f16 of code n=c*16+(lane&15),
//         k = s*32 + (lane>>4)*8 + 0..7.  hl=0 -> hi, hl=1 -> lo.
//   E2NEG: nch*256 B; wse[c*64 + j] = -||e_{c*16+(j&15)}||^2 (double-summed).
//   WSV:   4*N floats — per-slice best score.
//   WSI:   4*N ints   — per-slice best index.

__global__ void prep_kernel(const float* __restrict__ embed,
                            char* __restrict__ frag,
                            float* __restrict__ e2neg, int total) {
  int t = blockIdx.x * blockDim.x + threadIdx.x;
  if (t >= total) return;
  int lane = t & 63;
  int idx = (t >> 6) & 7;
  int c = t >> 9;
  int s = idx >> 1;
  int hl = idx & 1;
  int n = c * 16 + (lane & 15);
  int kb = s * 32 + ((lane >> 4) << 3);
  const float* src = embed + (size_t)n * DD + kb;
  _Float16* dst = (_Float16*)(frag + (size_t)c * 8192 + idx * 1024 + lane * 16);
#pragma unroll
  for (int j = 0; j < 8; ++j) {
    float v = src[j];
    _Float16 hi = (_Float16)v;
    dst[j] = hl ? (_Float16)(v - (float)hi) : hi;
  }
  if (idx == 0) {
    const float* e = embed + (size_t)n * DD;
    double acc = 0.0;
    for (int j = 0; j < DD; ++j) { double v = (double)e[j]; acc += v * v; }
    e2neg[c * 64 + lane] = (float)(-acc);
  }
}

// ---------------------------------------------------------------------------
// PASS 1: split-K-4. Block = 256 thr (4 waves x 32 rows = 128 rows), slice =
// blockIdx&3 covers 256 codes (16 chunks, 4 super-steps of 4). Per super-step:
// flat-stage 32 KB of B-frag records into LDS (256 thr x 8 x 16 B), ONE
// barrier, compute 4 chunks R2-verbatim (8x ds_read_b128 + 24x
// mfma_f32_16x16x32_f16 + fp32 epilogue), ONE barrier. 8 barriers total.
// __launch_bounds__(256,4) + 32 KB LDS -> 4 blocks/CU = 4 waves/SIMD = 8
// acc-chains/SIMD — the TLP config never yet tested with LDS-shared B
// (abl1 showed 2 waves/SIMD leaves the MFMA pipe ~45% idle even with zero
// loads; m114: cross-wave overlap works). Per-slice scores bit-identical to
// R2. 16-lane shuffle reduce, then (score,idx) written per (slice,row).
// C/D layout (verified): col=lane&15, row=(lane>>4)*4+reg.
// ---------------------------------------------------------------------------
__global__ __launch_bounds__(256, 4) void vq_pass1(
    const float* __restrict__ x, const char* __restrict__ wsf,
    const float* __restrict__ wse, float* __restrict__ wsv,
    int* __restrict__ wsi, int N) {
  const int tid = threadIdx.x;
  const int lane = tid & 63;
  const int w = tid >> 6;
  const int m16 = lane & 15;
  const int g = lane >> 4;
  const int rowblk = blockIdx.x >> 2;
  const int slice = blockIdx.x & 3;
  const int row0 = rowblk * 128 + w * 32;

  __shared__ alignas(16) char lds_b[32768];

  // A fragments for 2 row-tiles, f16 hi/lo split (R2-verbatim)
  half8 ah[2][4], al[2][4];
#pragma unroll
  for (int t = 0; t < 2; ++t) {
    const float* xrow = x + (size_t)(row0 + t * 16 + m16) * DD;
#pragma unroll
    for (int s = 0; s < 4; ++s) {
      const float* p = xrow + s * 32 + g * 8;
      f32x4 v0 = *(const f32x4*)(p);
      f32x4 v1 = *(const f32x4*)(p + 4);
#pragma unroll
      for (int j = 0; j < 4; ++j) {
        float v = v0[j];
        _Float16 hi = (_Float16)v;
        ah[t][s][j] = hi;
        al[t][s][j] = (_Float16)(v - (float)hi);
      }
#pragma unroll
      for (int j = 0; j < 4; ++j) {
        float v = v1[j];
        _Float16 hi = (_Float16)v;
        ah[t][s][4 + j] = hi;
        al[t][s][4 + j] = (_Float16)(v - (float)hi);
      }
    }
  }

  float bestv0[4], bestv1[4];
  int besti0[4], besti1[4];
#pragma unroll
  for (int r = 0; r < 4; ++r) {
    bestv0[r] = -__builtin_inff();
    bestv1[r] = -__builtin_inff();
    besti0[r] = 0;
    besti1[r] = 0;
  }

  for (int u = 0; u < 4; ++u) {
    // stage super-step u: 4 chunk-records, 32 KB flat copy
    {
      const char* gs = wsf + ((size_t)slice * 16 + u * 4) * 8192;
#pragma unroll
      for (int i = 0; i < 8; ++i) {
        const int off = (tid + i * 256) * 16;
        *(u32x4*)(lds_b + off) = *(const u32x4*)(gs + off);
      }
    }
    __syncthreads();

#pragma unroll
    for (int cc = 0; cc < 4; ++cc) {
      const int cg = slice * 16 + u * 4 + cc;
      const char* fb = lds_b + cc * 8192;
      half8 bh[4], bl[4];
#pragma unroll
      for (int s = 0; s < 4; ++s) {
        bh[s] = *(const half8*)(fb + (2 * s) * 1024 + lane * 16);
        bl[s] = *(const half8*)(fb + (2 * s + 1) * 1024 + lane * 16);
      }
      const float ne_ = wse[(size_t)cg * 64 + lane];

      f32x4 acc0 = {0.f, 0.f, 0.f, 0.f};
      f32x4 acc1 = {0.f, 0.f, 0.f, 0.f};
#pragma unroll
      for (int s = 0; s < 4; ++s) {  // R2-verbatim chain order
        acc0 = __builtin_amdgcn_mfma_f32_16x16x32_f16(ah[0][s], bh[s], acc0, 0,
                                                      0, 0);
        acc1 = __builtin_amdgcn_mfma_f32_16x16x32_f16(ah[1][s], bh[s], acc1, 0,
                                                      0, 0);
        acc0 = __builtin_amdgcn_mfma_f32_16x16x32_f16(al[0][s], bh[s], acc0, 0,
                                                      0, 0);
        acc1 = __builtin_amdgcn_mfma_f32_16x16x32_f16(al[1][s], bh[s], acc1, 0,
                                                      0, 0);
        acc0 = __builtin_amdgcn_mfma_f32_16x16x32_f16(ah[0][s], bl[s], acc0, 0,
                                                      0, 0);
        acc1 = __builtin_amdgcn_mfma_f32_16x16x32_f16(ah[1][s], bl[s], acc1, 0,
                                                      0, 0);
      }
      const int n_ = cg * 16 + m16;
#pragma unroll
      for (int r = 0; r < 4; ++r) {
        float s0 = fmaf(2.f, acc0[r], ne_);
        if (s0 > bestv0[r]) { bestv0[r] = s0; besti0[r] = n_; }
        float s1 = fmaf(2.f, acc1[r], ne_);
        if (s1 > bestv1[r]) { bestv1[r] = s1; besti1[r] = n_; }
      }
    }
    __syncthreads();  // before next super-step overwrites lds_b
  }

  // 16-lane shuffle reduce (R2-verbatim); smaller index on tie
#pragma unroll
  for (int off = 1; off < 16; off <<= 1) {
#pragma unroll
    for (int r = 0; r < 4; ++r) {
      float ov0 = __shfl_xor(bestv0[r], off, 64);
      int oi0 = __shfl_xor(besti0[r], off, 64);
      if (ov0 > bestv0[r] || (ov0 == bestv0[r] && oi0 < besti0[r])) {
        bestv0[r] = ov0;
        besti0[r] = oi0;
      }
      float ov1 = __shfl_xor(bestv1[r], off, 64);
      int oi1 = __shfl_xor(besti1[r], off, 64);
      if (ov1 > bestv1[r] || (ov1 == bestv1[r] && oi1 < besti1[r])) {
        bestv1[r] = ov1;
        besti1[r] = oi1;
      }
    }
  }

  // per-slice (score, index) out
  if (m16 == 0) {
#pragma unroll
    for (int t = 0; t < 2; ++t) {
#pragma unroll
      for (int r = 0; r < 4; ++r) {
        const int row = row0 + t * 16 + g * 4 + r;
        wsv[(size_t)slice * N + row] = t ? bestv1[r] : bestv0[r];
        wsi[(size_t)slice * N + row] = t ? besti1[r] : besti0[r];
      }
    }
  }
}

// ---------------------------------------------------------------------------
// PASS 2: merge 4 slices (ascending slice => first-max tie semantics over
// bit-exact fp32 scores) + write indices + coalesced gather.
// ---------------------------------------------------------------------------
__global__ __launch_bounds__(256) void vq_merge(
    const float* __restrict__ embed, const float* __restrict__ wsv,
    const int* __restrict__ wsi, float* __restrict__ out_q,
    float* __restrict__ out_i, int N) {
  const int tid = threadIdx.x;
  const int r = blockIdx.x * 256 + tid;
  __shared__ int idxs[256];

  float bv = -__builtin_inff();
  int bi = 0;
#pragma unroll
  for (int s = 0; s < 4; ++s) {
    float v = wsv[(size_t)s * N + r];
    int i = wsi[(size_t)s * N + r];
    if (v > bv || (v == bv && i < bi)) { bv = v; bi = i; }
  }
  out_i[r] = (float)bi;
  idxs[tid] = bi;
  __syncthreads();

  // gather: wave w handles rows [w*64, +64), 2 rows per iter (32 lanes each)
  const int w = tid >> 6;
  const int lane = tid & 63;
  const int l32 = lane & 31;
  const int hl = lane >> 5;
  const size_t rbase = (size_t)blockIdx.x * 256;
#pragma unroll 4
  for (int it = 0; it < 32; ++it) {
    const int lr = w * 64 + it * 2 + hl;
    const int idx = idxs[lr];
    f32x4 v = *((const f32x4*)(embed + (size_t)idx * DD) + l32);
    *((f32x4*)(out_q + (rbase + lr) * DD) + l32) = v;
  }
}

// ---------------------------------------------------------------------------
// Fallback: exact double-precision distance, thread per row.
// ---------------------------------------------------------------------------
__global__ void vq_fallback_kernel(const float* __restrict__ x,
                                   const float* __restrict__ embed,
                                   float* __restrict__ out_q,
                                   float* __restrict__ out_i, int N, int K) {
  int row = blockIdx.x * blockDim.x + threadIdx.x;
  if (row >= N) return;
  const float* xr = x + (size_t)row * DD;
  float xv[DD];
  for (int j = 0; j < DD; ++j) xv[j] = xr[j];
  double best = -1e300;
  int bi = 0;
  for (int k = 0; k < K; ++k) {
    const float* e = embed + (size_t)k * DD;
    double acc = 0.0;
    for (int j = 0; j < DD; ++j) {
      double d = (double)xv[j] - (double)e[j];
      acc += d * d;
    }
    double sc = -acc;
    if (sc > best) { best = sc; bi = k; }
  }
  out_i[row] = (float)bi;
  for (int j = 0; j < DD; ++j)
    out_q[(size_t)row * DD + j] = embed[(size_t)bi * DD + j];
}

extern "C" void kernel_launch(void* const* d_in, const int* in_sizes, int n_in,
                              void* d_out, int out_size, void* d_ws,
                              size_t ws_size, hipStream_t stream) {
  const float* x = (const float*)d_in[0];
  const float* embed = (const float*)d_in[1];
  const int N = in_sizes[0] / DD;  // 65536 rows
  const int K = in_sizes[1] / DD;  // 1024 codes
  float* out_q = (float*)d_out;
  float* out_i = out_q + (size_t)N * DD;

  const int nch = K / 16;
  const size_t frag_bytes = (size_t)nch * 8192;
  const size_t e2_bytes = (size_t)nch * 256;
  const size_t vi_bytes = (size_t)4 * N * 4;
  const size_t need = frag_bytes + e2_bytes + 2 * vi_bytes;

  if (ws_size < need || (N % 256) != 0 || (K % 256) != 0) {
    vq_fallback_kernel<<<(N + 255) / 256, 256, 0, stream>>>(x, embed, out_q,
                                                            out_i, N, K);
    return;
  }

  char* wsf = (char*)d_ws;
  float* wse = (float*)(wsf + frag_bytes);
  float* wsv = (float*)(wsf + frag_bytes + e2_bytes);
  int* wsi = (int*)(wsf + frag_bytes + e2_bytes + vi_bytes);

  const int total_f = nch * 8 * 64;
  prep_kernel<<<(total_f + 255) / 256, 256, 0, stream>>>(embed, wsf, wse,
                                                         total_f);
  vq_pass1<<<(N / 128) * 4, 256, 0, stream>>>(x, wsf, wse, wsv, wsi, N);
  vq_merge<<<N / 256, 256, 0, stream>>>(embed, wsv, wsi, out_q, out_i, N);
}